// Round 14
// baseline (2252.634 us; speedup 1.0000x reference)
//
#include <hip/hip_runtime.h>
#include <hip/hip_bf16.h>

#define B_   32
#define T_   512
#define E_   300
#define H_   256
#define OUT_ 256
#define ECH  100    // gemm e-chunk (3 x 100 = 300)
#define GROWP 293   // gbuf row stride; conflict-free (banks 5rg+4bgr cover all 32)

typedef unsigned long long u64;

// ---------------------------------------------------------------------------
// Slot tables, LDS-staged (unchanged).
// ---------------------------------------------------------------------------
__global__ __launch_bounds__(64) void slots_kernel(
    const unsigned char* __restrict__ fm, const unsigned char* __restrict__ bm,
    int* __restrict__ fslot, int* __restrict__ bpos)
{
    __shared__ unsigned char fL[B_ * T_];
    __shared__ unsigned char bL[B_ * T_];
    const int tid = threadIdx.x;

    const unsigned int* fw = (const unsigned int*)fm;
    int cnt = 0;
    for (int i = tid; i < 128; i += 64) {
        unsigned int v = fw[i];
        cnt += ((v & 0xFFu) != 0) + ((v & 0xFF00u) != 0)
             + ((v & 0xFF0000u) != 0) + ((v >> 24) != 0);
    }
#pragma unroll
    for (int off = 32; off; off >>= 1) cnt += __shfl_down(cnt, off, 64);
    bool isbool = __shfl(cnt, 0, 64) > 128;

    if (isbool) {
        for (int i = tid; i < B_ * T_ / 4; i += 64) {
            ((unsigned int*)fL)[i] = ((const unsigned int*)fm)[i];
            ((unsigned int*)bL)[i] = ((const unsigned int*)bm)[i];
        }
    } else {
        const unsigned int* bw = (const unsigned int*)bm;
        for (int i = tid; i < B_ * T_; i += 64) {
            fL[i] = fw[i] != 0;
            bL[i] = bw[i] != 0;
        }
    }
    __syncthreads();

    if (tid < B_) {
        int jf = 0, jb = 0;
        for (int t = 0; t < T_; ++t) {
            bool f = fL[tid * T_ + t] != 0;
            bool g = bL[tid * T_ + t] != 0;
            fslot[tid * T_ + t] = f ? (jf++) : -1;
            bpos [tid * T_ + t] = g ? (OUT_ - 1 - (jb++)) : -1;
        }
    }
}

// ---------------------------------------------------------------------------
// Standalone xg GEMM — fallback only (ws too small for full-T xg buffer).
// ---------------------------------------------------------------------------
__global__ __launch_bounds__(256) void xg_gemm(
    const int* __restrict__ inputs, const int* __restrict__ seqlen,
    const float* __restrict__ emb,
    const float* __restrict__ Wihf, const float* __restrict__ Wihb,
    const float* __restrict__ bihf, const float* __restrict__ bhhf,
    const float* __restrict__ bihb, const float* __restrict__ bhhb,
    float* __restrict__ xg, int t0, int TcMax)
{
    const int tg   = blockIdx.y;
    const int dir  = blockIdx.z;
    const int rblk = blockIdx.x * 64;
    const int tid  = threadIdx.x;

    __shared__ float eL[4][B_][ECH];
    __shared__ int   tokS[4][B_];

    if (tid < 128) {
        int t4 = tid >> 5, b = tid & 31;
        int t = t0 + tg * 4 + t4;
        int L = seqlen[b];
        int tt = t;
        if (dir) tt = (t < L) ? (L - 1 - t) : t;
        tokS[t4][b] = inputs[b * T_ + tt];
    }

    const float* W = dir ? Wihb : Wihf;
    const int b  = tid & 31;
    const int r8 = tid >> 5;

    float acc[4][8];
#pragma unroll
    for (int t4 = 0; t4 < 4; ++t4)
#pragma unroll
        for (int m = 0; m < 8; ++m) acc[t4][m] = 0.f;

    for (int ec = 0; ec < 3; ++ec) {
        __syncthreads();
        for (int idx = tid; idx < 3200; idx += 256) {
            int q  = idx % 25;
            int bb = (idx / 25) & 31;
            int t4 = idx / (25 * 32);
            const float* erow = emb + (size_t)tokS[t4][bb] * E_ + ec * ECH;
            *(float4*)&eL[t4][bb][q * 4] = *(const float4*)(erow + q * 4);
        }
        __syncthreads();

        for (int e4 = 0; e4 < 25; ++e4) {
            float4 w4[8];
#pragma unroll
            for (int m = 0; m < 8; ++m)
                w4[m] = *(const float4*)(W + (size_t)(rblk + r8 + m * 8) * E_
                                         + ec * ECH + e4 * 4);
#pragma unroll
            for (int t4 = 0; t4 < 4; ++t4) {
                float4 h4 = *(const float4*)&eL[t4][b][e4 * 4];
#pragma unroll
                for (int m = 0; m < 8; ++m)
                    acc[t4][m] += h4.x * w4[m].x + h4.y * w4[m].y
                                + h4.z * w4[m].z + h4.w * w4[m].w;
            }
        }
    }

    const float* bi = dir ? bihb : bihf;
    const float* bh = dir ? bhhb : bhhf;
#pragma unroll
    for (int t4 = 0; t4 < 4; ++t4) {
        float* outp = xg + (size_t)(dir * TcMax + tg * 4 + t4) * (1024 * B_);
#pragma unroll
        for (int m = 0; m < 8; ++m) {
            int row = rblk + r8 + m * 8;
            outp[(size_t)row * B_ + b] = acc[t4][m] + bi[row] + bh[row];
        }
    }
}

// ---------------------------------------------------------------------------
// Fused kernel v4. vs r13:
//  (1) frozen-path h comes from a REGISTER (h_own = own previously published
//      value) -> epilogue never reads hP -> post-publish barrier DELETED.
//      Waves 2-7 start next-step packet discovery immediately after the
//      post-dot barrier, overlapping waves 0-1's epilogue+publish.
//      Tag protocol still safe: publish(t) follows own [A](t) loads
//      (barrier 1), so tags==t observed implies slot (t-2) fully consumed.
//  (2) selective retry: reload only stale packet indices (bitmask) ->
//      retry ~4 loads instead of 16 (r13 FETCH 465MB -> ~370 expected).
// ---------------------------------------------------------------------------
__global__ __launch_bounds__(512, 2) void fused_lstm(
    const int* __restrict__ inputs, const int* __restrict__ seqlen,
    const float* __restrict__ emb,
    const float* __restrict__ Wihf, const float* __restrict__ Whhf,
    const float* __restrict__ bihf, const float* __restrict__ bhhf,
    const float* __restrict__ Wihb, const float* __restrict__ Whhb,
    const float* __restrict__ bihb, const float* __restrict__ bhhb,
    const int* __restrict__ fslot, const int* __restrict__ bpos,
    u64* __restrict__ hbuf, float* __restrict__ cbuf,
    int* __restrict__ xgcnt, float* __restrict__ xg, float* __restrict__ out,
    int t0, int Tc, int fused)
{
    const int wg  = blockIdx.x;
    const int tid = threadIdx.x;
    __shared__ __align__(16) float smem[13824];   // 55.3 KB, carved per role

    if (wg >= 128) {
        // ---------------- producer role (fused mode only) ----------------
        float* eL   = smem;                        // [4][32][ECH] = 12800 f
        int*   tokS = (int*)(smem + 12800);        // [4][32]
        const int hw = wg - 128;

        for (int j = hw; j < 2048; j += 128) {     // job: (tg, dir, rblk-pair)
            const int tg  = j >> 4;
            const int dir = (j >> 3) & 1;
            const int rp  = j & 7;
            const int rblk = (rp * 2 + (tid >> 8)) * 64;

            if (tid < 128) {
                int t4 = tid >> 5, b = tid & 31;
                int t = tg * 4 + t4;
                int L = seqlen[b];
                int tt = t;
                if (dir) tt = (t < L) ? (L - 1 - t) : t;
                tokS[t4 * B_ + b] = inputs[b * T_ + tt];
            }

            const float* W  = dir ? Wihb : Wihf;
            const int ltid = tid & 255;
            const int b  = ltid & 31;
            const int r8 = ltid >> 5;

            float acc[4][8];
#pragma unroll
            for (int t4 = 0; t4 < 4; ++t4)
#pragma unroll
                for (int m = 0; m < 8; ++m) acc[t4][m] = 0.f;

            for (int ec = 0; ec < 3; ++ec) {
                __syncthreads();   // tokS ready / eL consumed
                for (int idx = tid; idx < 3200; idx += 512) {
                    int q  = idx % 25;
                    int bb = (idx / 25) & 31;
                    int t4 = idx / (25 * 32);
                    const float* erow = emb + (size_t)tokS[t4 * B_ + bb] * E_ + ec * ECH;
                    *(float4*)&eL[(t4 * B_ + bb) * ECH + q * 4] = *(const float4*)(erow + q * 4);
                }
                __syncthreads();

                for (int e4 = 0; e4 < 25; ++e4) {
                    float4 w4[8];
#pragma unroll
                    for (int m = 0; m < 8; ++m)
                        w4[m] = *(const float4*)(W + (size_t)(rblk + r8 + m * 8) * E_
                                                 + ec * ECH + e4 * 4);
#pragma unroll
                    for (int t4 = 0; t4 < 4; ++t4) {
                        float4 h4 = *(const float4*)&eL[(t4 * B_ + b) * ECH + e4 * 4];
#pragma unroll
                        for (int m = 0; m < 8; ++m)
                            acc[t4][m] += h4.x * w4[m].x + h4.y * w4[m].y
                                        + h4.z * w4[m].z + h4.w * w4[m].w;
                    }
                }
            }

            const float* bi = dir ? bihb : bihf;
            const float* bh = dir ? bhhb : bhhf;
#pragma unroll
            for (int t4 = 0; t4 < 4; ++t4) {
                float* outp = xg + (size_t)(dir * 512 + tg * 4 + t4) * (1024 * B_);
#pragma unroll
                for (int m = 0; m < 8; ++m) {
                    int row = rblk + r8 + m * 8;
                    __hip_atomic_store(&outp[(size_t)row * B_ + b],
                                       acc[t4][m] + bi[row] + bh[row],
                                       __ATOMIC_RELAXED, __HIP_MEMORY_SCOPE_AGENT);
                }
            }
            __syncthreads();   // per-wave vmcnt(0): all bypass stores at LLC
            if (tid == 0)
                __hip_atomic_fetch_add(&xgcnt[dir * 128 + tg], 1,
                                       __ATOMIC_RELAXED, __HIP_MEMORY_SCOPE_AGENT);
        }
        return;
    }

    // ------------------------- recurrence role -------------------------
    float* hP   = smem;                      // 8704 f (34.8 KB)
    float* gbuf = smem + 8704;               // 16*GROWP = 4688 f
    int*   sL   = (int*)(smem + 8704 + 4688);

    const int dir = wg >> 6;
    const int wgd = wg & 63;
    const int u0  = wgd * 4;

    const int rg  = tid & 3;
    const int bgr = (tid >> 2) & 7;
    const int kq  = tid >> 5;

    const float* Whh = dir ? Whhb : Whhf;

    float w[4][16];
#pragma unroll
    for (int r = 0; r < 4; ++r) {
        const float* wr = Whh + (size_t)(rg * H_ + u0 + r) * H_ + kq * 16;
#pragma unroll
        for (int q = 0; q < 4; ++q) {
            float4 v = *(const float4*)(wr + q * 4);
            w[r][q * 4 + 0] = v.x; w[r][q * 4 + 1] = v.y;
            w[r][q * 4 + 2] = v.z; w[r][q * 4 + 3] = v.w;
        }
    }
    if (tid < B_) sL[tid] = seqlen[tid];
    __syncthreads();

    const int ul = (tid >> 5) & 3, bb = tid & 31;
    float c_reg = 0.f;
    float h_own = 0.f;                       // own published h (frozen path)
    if (t0 > 0 && tid < 128) {
        c_reg = cbuf[(size_t)(dir * 64 + wgd) * 128 + ul * 32 + bb];
        // re-seed h_own from previous chunk's packet (tag == t0, landed)
        u64 p = __hip_atomic_load(
            hbuf + (size_t)(dir * 2 + ((t0 - 1) & 1)) * 8192 + wgd * 128 + tid,
            __ATOMIC_RELAXED, __HIP_MEMORY_SCOPE_AGENT);
        h_own = __uint_as_float((unsigned)p);
    }

    // initial xg: gate group t0>>2 (fused), then load xg(t0), xg(t0+1)
    if (fused) {
        if (tid == 0) {
            const int* xc = xgcnt + dir * 128 + (t0 >> 2);
            while (__hip_atomic_load(xc, __ATOMIC_RELAXED,
                                     __HIP_MEMORY_SCOPE_AGENT) < 8)
                __builtin_amdgcn_s_sleep(1);
        }
        __syncthreads();
    }
    float xv0 = 0.f, xv1 = 0.f, xv2 = 0.f, xv3 = 0.f;   // xg(t)
    float ya0 = 0.f, ya1 = 0.f, ya2 = 0.f, ya3 = 0.f;   // xg(t+1)
    if (tid < 128) {
        const float* xp = xg + (size_t)(dir * Tc) * 32768 + (u0 + ul) * 32 + bb;
        xv0 = __hip_atomic_load(xp,         __ATOMIC_RELAXED, __HIP_MEMORY_SCOPE_AGENT);
        xv1 = __hip_atomic_load(xp +  8192, __ATOMIC_RELAXED, __HIP_MEMORY_SCOPE_AGENT);
        xv2 = __hip_atomic_load(xp + 16384, __ATOMIC_RELAXED, __HIP_MEMORY_SCOPE_AGENT);
        xv3 = __hip_atomic_load(xp + 24576, __ATOMIC_RELAXED, __HIP_MEMORY_SCOPE_AGENT);
        if (Tc > 1) {
            const float* xq = xp + 32768;
            ya0 = __hip_atomic_load(xq,         __ATOMIC_RELAXED, __HIP_MEMORY_SCOPE_AGENT);
            ya1 = __hip_atomic_load(xq +  8192, __ATOMIC_RELAXED, __HIP_MEMORY_SCOPE_AGENT);
            ya2 = __hip_atomic_load(xq + 16384, __ATOMIC_RELAXED, __HIP_MEMORY_SCOPE_AGENT);
            ya3 = __hip_atomic_load(xq + 24576, __ATOMIC_RELAXED, __HIP_MEMORY_SCOPE_AGENT);
        }
    }

    for (int tc = 0; tc < Tc; ++tc) {
        const int t = t0 + tc;

        // [A] discovery + load h(t-1); selective retry of stale packets only.
        // Waves 2-7 reach here straight from the post-dot barrier of step
        // t-1, overlapping waves 0-1's epilogue+publish of step t-1.
        if (t > 0) {
            const u64* hp = hbuf + (size_t)(dir * 2 + ((t - 1) & 1)) * 8192;
            u64 hr[16];
#pragma unroll
            for (int i = 0; i < 16; ++i)
                hr[i] = __hip_atomic_load(hp + tid + 512 * i, __ATOMIC_RELAXED,
                                          __HIP_MEMORY_SCOPE_AGENT);
            for (;;) {
                unsigned bad = 0;
#pragma unroll
                for (int i = 0; i < 16; ++i)
                    if ((unsigned)(hr[i] >> 32) != (unsigned)t) bad |= (1u << i);
                if (__all(bad == 0)) break;
                __builtin_amdgcn_s_sleep(1);
#pragma unroll
                for (int i = 0; i < 16; ++i)
                    if (bad & (1u << i))
                        hr[i] = __hip_atomic_load(hp + tid + 512 * i,
                                                  __ATOMIC_RELAXED,
                                                  __HIP_MEMORY_SCOPE_AGENT);
            }
#pragma unroll
            for (int i = 0; i < 16; ++i) {
                int wdx = tid + 512 * i;                      // word 0..8191
                int k = ((wdx >> 7) << 2) | ((wdx >> 5) & 3); // unit
                int b = wdx & 31;                             // batch
                hP[((k >> 4) * 8 + (b >> 2)) * 68 + (k & 15) * 4 + (b & 3)] =
                    __uint_as_float((unsigned)hr[i]);
            }
        }
        __syncthreads();   // barrier 1: hP ready

        // non-blocking xgcnt peek for t+2 (waitcnt lands under the dot)
        int cnt = 8;
        if (fused && tc + 2 < Tc && tid < 128)
            cnt = __hip_atomic_load(xgcnt + dir * 128 + ((t0 + tc + 2) >> 2),
                                    __ATOMIC_RELAXED, __HIP_MEMORY_SCOPE_AGENT);

        // [B] dot (W from registers, h from conflict-free hP blocks)
        float acc[4][4];
#pragma unroll
        for (int r = 0; r < 4; ++r)
#pragma unroll
            for (int bi = 0; bi < 4; ++bi) acc[r][bi] = 0.f;

        if (t > 0) {
            const float* hblk = &hP[(kq * 8 + bgr) * 68];
#pragma unroll
            for (int kk = 0; kk < 16; ++kk) {
                float4 h4 = *(const float4*)(hblk + kk * 4);
#pragma unroll
                for (int r = 0; r < 4; ++r) {
                    acc[r][0] += w[r][kk] * h4.x;
                    acc[r][1] += w[r][kk] * h4.y;
                    acc[r][2] += w[r][kk] * h4.z;
                    acc[r][3] += w[r][kk] * h4.w;
                }
            }
        }

#pragma unroll
        for (int r = 0; r < 4; ++r)
#pragma unroll
            for (int bi = 0; bi < 4; ++bi)
                acc[r][bi] += __shfl_xor(acc[r][bi], 32, 64);

        if (((tid >> 5) & 1) == 0) {
            const int kq2 = kq >> 1;
#pragma unroll
            for (int r = 0; r < 4; ++r)
#pragma unroll
                for (int bi = 0; bi < 4; ++bi)
                    gbuf[(r * 4 + rg) * GROWP + (bgr * 4 + bi) * 9 + kq2] = acc[r][bi];
        }
        __syncthreads();   // barrier 2: gbuf ready; hP reads complete

        // [C] waves 0-1: epilogue + publish + out + xg prefetch.
        // No barrier after this — waves 2-7 are already in [A] of t+1.
        // Safe: epilogue reads gbuf/registers only (hP untouched); next-step
        // gbuf writes happen after barrier 1 of t+1, which waits for us.
        if (tid < 128) {
            const int u = u0 + ul;
            float hnew;
            float* oaddr = nullptr;
            if (t < sL[bb]) {
                float gi = xv0, gf = xv1, gg = xv2, go = xv3;
#pragma unroll
                for (int q = 0; q < 8; ++q) {
                    gi += gbuf[(ul * 4 + 0) * GROWP + bb * 9 + q];
                    gf += gbuf[(ul * 4 + 1) * GROWP + bb * 9 + q];
                    gg += gbuf[(ul * 4 + 2) * GROWP + bb * 9 + q];
                    go += gbuf[(ul * 4 + 3) * GROWP + bb * 9 + q];
                }
                float si = 1.f / (1.f + expf(-gi));
                float sf = 1.f / (1.f + expf(-gf));
                float so = 1.f / (1.f + expf(-go));
                c_reg = sf * c_reg + si * tanhf(gg);
                hnew  = so * tanhf(c_reg);
                if (dir == 0) {
                    int j = fslot[bb * T_ + t];
                    if (j >= 0) oaddr = &out[((size_t)bb * OUT_ + j) * 512 + u];
                } else {
                    int p = bpos[bb * T_ + t];
                    if (p >= 0) oaddr = &out[((size_t)bb * OUT_ + p) * 512 + 256 + u];
                }
            } else {
                hnew = h_own;   // frozen: own previously published value
            }
            h_own = hnew;
            // self-validating packet: {tag = t+1, value}; coalesced 1 KB
            u64 pkt = ((u64)(unsigned)(t + 1) << 32) | (u64)__float_as_uint(hnew);
            u64* hn = hbuf + (size_t)(dir * 2 + (t & 1)) * 8192;
            __hip_atomic_store(&hn[wgd * 128 + tid], pkt,
                               __ATOMIC_RELAXED, __HIP_MEMORY_SCOPE_AGENT);

            // off-critical tail: out scatter + xg(t+2) load (+rare gate)
            if (oaddr)
                __hip_atomic_store(oaddr, hnew, __ATOMIC_RELAXED,
                                   __HIP_MEMORY_SCOPE_AGENT);
            float z0 = 0.f, z1 = 0.f, z2 = 0.f, z3 = 0.f;
            if (tc + 2 < Tc) {
                if (fused && cnt < 8) {
                    const int* xc = xgcnt + dir * 128 + ((t0 + tc + 2) >> 2);
                    while (__hip_atomic_load(xc, __ATOMIC_RELAXED,
                                             __HIP_MEMORY_SCOPE_AGENT) < 8)
                        __builtin_amdgcn_s_sleep(1);
                }
                const float* xp = xg + (size_t)(dir * Tc + tc + 2) * 32768
                                  + (u0 + ul) * 32 + bb;
                z0 = __hip_atomic_load(xp,         __ATOMIC_RELAXED, __HIP_MEMORY_SCOPE_AGENT);
                z1 = __hip_atomic_load(xp +  8192, __ATOMIC_RELAXED, __HIP_MEMORY_SCOPE_AGENT);
                z2 = __hip_atomic_load(xp + 16384, __ATOMIC_RELAXED, __HIP_MEMORY_SCOPE_AGENT);
                z3 = __hip_atomic_load(xp + 24576, __ATOMIC_RELAXED, __HIP_MEMORY_SCOPE_AGENT);
            }
            xv0 = ya0; xv1 = ya1; xv2 = ya2; xv3 = ya3;
            ya0 = z0;  ya1 = z1;  ya2 = z2;  ya3 = z3;
        }
    }

    if (tid < 128)
        cbuf[(size_t)(dir * 64 + wgd) * 128 + ul * 32 + bb] = c_reg;
}

// ---------------------------------------------------------------------------
extern "C" void kernel_launch(void* const* d_in, const int* in_sizes, int n_in,
                              void* d_out, int out_size, void* d_ws, size_t ws_size,
                              hipStream_t stream) {
    const int*           inputs = (const int*)d_in[0];
    const int*           seqlen = (const int*)d_in[1];
    const unsigned char* fm     = (const unsigned char*)d_in[2];
    const unsigned char* bm     = (const unsigned char*)d_in[3];
    // d_in[4] = out_seq_length (== 256, hardcoded)
    const float* emb  = (const float*)d_in[5];
    const float* Wihf = (const float*)d_in[6];
    const float* Whhf = (const float*)d_in[7];
    const float* bihf = (const float*)d_in[8];
    const float* bhhf = (const float*)d_in[9];
    const float* Wihb = (const float*)d_in[10];
    const float* Whhb = (const float*)d_in[11];
    const float* bihb = (const float*)d_in[12];
    const float* bhhb = (const float*)d_in[13];
    float* out = (float*)d_out;

    char* ws = (char*)d_ws;
    // ws layout (bytes):
    //   [0)       fslot int32[32][512]                       65536
    //   [65536)   bpos  int32[32][512]                       65536
    //   [131072)  h packets u64[2dir][2par][8192]           262144
    //   [393216)  c checkpoint f32[2dir][64][4][32]          65536
    //   [458752)  xgcnt int32[2dir][128]                      1024
    //   [460800)  xg f32[2dir][Tc][1024][32]            Tc*262144
    int*   fslot = (int*)(ws);
    int*   bpos  = (int*)(ws + 65536);
    u64*   hbuf  = (u64*)(ws + 131072);
    float* cbuf  = (float*)(ws + 393216);
    int*   xgcnt = (int*)(ws + 458752);
    float* xg    = (float*)(ws + 460800);
    (void)in_sizes; (void)n_in; (void)out_size;

    size_t avail = (ws_size > 460800) ? ws_size - 460800 : 0;
    int Tc = 4;
    for (int c = 512; c >= 4; c >>= 1)
        if ((size_t)c * 262144 <= avail) { Tc = c; break; }

    // zero packet tags + xg counters every call (replay-safe: tag 0 is
    // never a valid expected tag since published tags are t+1 >= 1)
    (void)hipMemsetAsync(ws + 131072, 0, 262144, stream);
    (void)hipMemsetAsync(ws + 458752, 0, 1024, stream);
    slots_kernel<<<1, 64, 0, stream>>>(fm, bm, fslot, bpos);

    if (Tc == 512) {
        // fused: 128 recurrence WGs + 128 xg-producer WGs, one launch
        fused_lstm<<<256, 512, 0, stream>>>(
            inputs, seqlen, emb, Wihf, Whhf, bihf, bhhf,
            Wihb, Whhb, bihb, bhhb, fslot, bpos,
            hbuf, cbuf, xgcnt, xg, out, 0, 512, 1);
    } else {
        // fallback: chunked, separate gemm kernel (tags use global t, so
        // they remain consistent across chunk launches)
        for (int t0 = 0; t0 < T_; t0 += Tc) {
            dim3 g(16, Tc / 4, 2);
            xg_gemm<<<g, 256, 0, stream>>>(inputs, seqlen, emb, Wihf, Wihb,
                                           bihf, bhhf, bihb, bhhb, xg, t0, Tc);
            fused_lstm<<<128, 512, 0, stream>>>(
                inputs, seqlen, emb, Wihf, Whhf, bihf, bhhf,
                Wihb, Whhb, bihb, bhhb, fslot, bpos,
                hbuf, cbuf, xgcnt, xg, out, t0, Tc, 0);
        }
    }
}

// Round 15
// 2121.792 us; speedup vs baseline: 1.0617x; 1.0617x over previous
//
#include <hip/hip_runtime.h>
#include <hip/hip_bf16.h>

#define B_   32
#define T_   512
#define E_   300
#define H_   256
#define OUT_ 256
#define ECH  100    // gemm e-chunk (3 x 100 = 300)
#define GROWP 293   // gbuf row stride; conflict-free (banks 5rg+4bgr cover all 32)

typedef unsigned long long u64;

// ---------------------------------------------------------------------------
// Slot tables, LDS-staged (unchanged).
// ---------------------------------------------------------------------------
__global__ __launch_bounds__(64) void slots_kernel(
    const unsigned char* __restrict__ fm, const unsigned char* __restrict__ bm,
    int* __restrict__ fslot, int* __restrict__ bpos)
{
    __shared__ unsigned char fL[B_ * T_];
    __shared__ unsigned char bL[B_ * T_];
    const int tid = threadIdx.x;

    const unsigned int* fw = (const unsigned int*)fm;
    int cnt = 0;
    for (int i = tid; i < 128; i += 64) {
        unsigned int v = fw[i];
        cnt += ((v & 0xFFu) != 0) + ((v & 0xFF00u) != 0)
             + ((v & 0xFF0000u) != 0) + ((v >> 24) != 0);
    }
#pragma unroll
    for (int off = 32; off; off >>= 1) cnt += __shfl_down(cnt, off, 64);
    bool isbool = __shfl(cnt, 0, 64) > 128;

    if (isbool) {
        for (int i = tid; i < B_ * T_ / 4; i += 64) {
            ((unsigned int*)fL)[i] = ((const unsigned int*)fm)[i];
            ((unsigned int*)bL)[i] = ((const unsigned int*)bm)[i];
        }
    } else {
        const unsigned int* bw = (const unsigned int*)bm;
        for (int i = tid; i < B_ * T_; i += 64) {
            fL[i] = fw[i] != 0;
            bL[i] = bw[i] != 0;
        }
    }
    __syncthreads();

    if (tid < B_) {
        int jf = 0, jb = 0;
        for (int t = 0; t < T_; ++t) {
            bool f = fL[tid * T_ + t] != 0;
            bool g = bL[tid * T_ + t] != 0;
            fslot[tid * T_ + t] = f ? (jf++) : -1;
            bpos [tid * T_ + t] = g ? (OUT_ - 1 - (jb++)) : -1;
        }
    }
}

// ---------------------------------------------------------------------------
// Standalone xg GEMM — fallback only (ws too small for full-T xg buffer).
// ---------------------------------------------------------------------------
__global__ __launch_bounds__(256) void xg_gemm(
    const int* __restrict__ inputs, const int* __restrict__ seqlen,
    const float* __restrict__ emb,
    const float* __restrict__ Wihf, const float* __restrict__ Wihb,
    const float* __restrict__ bihf, const float* __restrict__ bhhf,
    const float* __restrict__ bihb, const float* __restrict__ bhhb,
    float* __restrict__ xg, int t0, int TcMax)
{
    const int tg   = blockIdx.y;
    const int dir  = blockIdx.z;
    const int rblk = blockIdx.x * 64;
    const int tid  = threadIdx.x;

    __shared__ float eL[4][B_][ECH];
    __shared__ int   tokS[4][B_];

    if (tid < 128) {
        int t4 = tid >> 5, b = tid & 31;
        int t = t0 + tg * 4 + t4;
        int L = seqlen[b];
        int tt = t;
        if (dir) tt = (t < L) ? (L - 1 - t) : t;
        tokS[t4][b] = inputs[b * T_ + tt];
    }

    const float* W = dir ? Wihb : Wihf;
    const int b  = tid & 31;
    const int r8 = tid >> 5;

    float acc[4][8];
#pragma unroll
    for (int t4 = 0; t4 < 4; ++t4)
#pragma unroll
        for (int m = 0; m < 8; ++m) acc[t4][m] = 0.f;

    for (int ec = 0; ec < 3; ++ec) {
        __syncthreads();
        for (int idx = tid; idx < 3200; idx += 256) {
            int q  = idx % 25;
            int bb = (idx / 25) & 31;
            int t4 = idx / (25 * 32);
            const float* erow = emb + (size_t)tokS[t4][bb] * E_ + ec * ECH;
            *(float4*)&eL[t4][bb][q * 4] = *(const float4*)(erow + q * 4);
        }
        __syncthreads();

        for (int e4 = 0; e4 < 25; ++e4) {
            float4 w4[8];
#pragma unroll
            for (int m = 0; m < 8; ++m)
                w4[m] = *(const float4*)(W + (size_t)(rblk + r8 + m * 8) * E_
                                         + ec * ECH + e4 * 4);
#pragma unroll
            for (int t4 = 0; t4 < 4; ++t4) {
                float4 h4 = *(const float4*)&eL[t4][b][e4 * 4];
#pragma unroll
                for (int m = 0; m < 8; ++m)
                    acc[t4][m] += h4.x * w4[m].x + h4.y * w4[m].y
                                + h4.z * w4[m].z + h4.w * w4[m].w;
            }
        }
    }

    const float* bi = dir ? bihb : bihf;
    const float* bh = dir ? bhhb : bhhf;
#pragma unroll
    for (int t4 = 0; t4 < 4; ++t4) {
        float* outp = xg + (size_t)(dir * TcMax + tg * 4 + t4) * (1024 * B_);
#pragma unroll
        for (int m = 0; m < 8; ++m) {
            int row = rblk + r8 + m * 8;
            outp[(size_t)row * B_ + b] = acc[t4][m] + bi[row] + bh[row];
        }
    }
}

// ---------------------------------------------------------------------------
// Fused kernel v5 = r13 structure (best measured) + SELECTIVE retry only.
// r14's barrier removal regressed (spin-loads contend with publish stores);
// the post-publish barrier is kept as a spin throttle + hP guard.
// Tag-in-data packets {tag=t+1, f32} via LLC-bypass; ping-pong + tags make
// overwrite race-free; tag 0 (memset) never valid -> replay-safe.
// ---------------------------------------------------------------------------
__global__ __launch_bounds__(512, 2) void fused_lstm(
    const int* __restrict__ inputs, const int* __restrict__ seqlen,
    const float* __restrict__ emb,
    const float* __restrict__ Wihf, const float* __restrict__ Whhf,
    const float* __restrict__ bihf, const float* __restrict__ bhhf,
    const float* __restrict__ Wihb, const float* __restrict__ Whhb,
    const float* __restrict__ bihb, const float* __restrict__ bhhb,
    const int* __restrict__ fslot, const int* __restrict__ bpos,
    u64* __restrict__ hbuf, float* __restrict__ cbuf,
    int* __restrict__ xgcnt, float* __restrict__ xg, float* __restrict__ out,
    int t0, int Tc, int fused)
{
    const int wg  = blockIdx.x;
    const int tid = threadIdx.x;
    __shared__ __align__(16) float smem[13824];   // 55.3 KB, carved per role

    if (wg >= 128) {
        // ---------------- producer role (fused mode only) ----------------
        float* eL   = smem;                        // [4][32][ECH] = 12800 f
        int*   tokS = (int*)(smem + 12800);        // [4][32]
        const int hw = wg - 128;

        for (int j = hw; j < 2048; j += 128) {     // job: (tg, dir, rblk-pair)
            const int tg  = j >> 4;
            const int dir = (j >> 3) & 1;
            const int rp  = j & 7;
            const int rblk = (rp * 2 + (tid >> 8)) * 64;

            if (tid < 128) {
                int t4 = tid >> 5, b = tid & 31;
                int t = tg * 4 + t4;
                int L = seqlen[b];
                int tt = t;
                if (dir) tt = (t < L) ? (L - 1 - t) : t;
                tokS[t4 * B_ + b] = inputs[b * T_ + tt];
            }

            const float* W  = dir ? Wihb : Wihf;
            const int ltid = tid & 255;
            const int b  = ltid & 31;
            const int r8 = ltid >> 5;

            float acc[4][8];
#pragma unroll
            for (int t4 = 0; t4 < 4; ++t4)
#pragma unroll
                for (int m = 0; m < 8; ++m) acc[t4][m] = 0.f;

            for (int ec = 0; ec < 3; ++ec) {
                __syncthreads();   // tokS ready / eL consumed
                for (int idx = tid; idx < 3200; idx += 512) {
                    int q  = idx % 25;
                    int bb = (idx / 25) & 31;
                    int t4 = idx / (25 * 32);
                    const float* erow = emb + (size_t)tokS[t4 * B_ + bb] * E_ + ec * ECH;
                    *(float4*)&eL[(t4 * B_ + bb) * ECH + q * 4] = *(const float4*)(erow + q * 4);
                }
                __syncthreads();

                for (int e4 = 0; e4 < 25; ++e4) {
                    float4 w4[8];
#pragma unroll
                    for (int m = 0; m < 8; ++m)
                        w4[m] = *(const float4*)(W + (size_t)(rblk + r8 + m * 8) * E_
                                                 + ec * ECH + e4 * 4);
#pragma unroll
                    for (int t4 = 0; t4 < 4; ++t4) {
                        float4 h4 = *(const float4*)&eL[(t4 * B_ + b) * ECH + e4 * 4];
#pragma unroll
                        for (int m = 0; m < 8; ++m)
                            acc[t4][m] += h4.x * w4[m].x + h4.y * w4[m].y
                                        + h4.z * w4[m].z + h4.w * w4[m].w;
                    }
                }
            }

            const float* bi = dir ? bihb : bihf;
            const float* bh = dir ? bhhb : bhhf;
#pragma unroll
            for (int t4 = 0; t4 < 4; ++t4) {
                float* outp = xg + (size_t)(dir * 512 + tg * 4 + t4) * (1024 * B_);
#pragma unroll
                for (int m = 0; m < 8; ++m) {
                    int row = rblk + r8 + m * 8;
                    __hip_atomic_store(&outp[(size_t)row * B_ + b],
                                       acc[t4][m] + bi[row] + bh[row],
                                       __ATOMIC_RELAXED, __HIP_MEMORY_SCOPE_AGENT);
                }
            }
            __syncthreads();   // per-wave vmcnt(0): all bypass stores at LLC
            if (tid == 0)
                __hip_atomic_fetch_add(&xgcnt[dir * 128 + tg], 1,
                                       __ATOMIC_RELAXED, __HIP_MEMORY_SCOPE_AGENT);
        }
        return;
    }

    // ------------------------- recurrence role -------------------------
    float* hP   = smem;                      // 8704 f (34.8 KB)
    float* gbuf = smem + 8704;               // 16*GROWP = 4688 f
    int*   sL   = (int*)(smem + 8704 + 4688);

    const int dir = wg >> 6;
    const int wgd = wg & 63;
    const int u0  = wgd * 4;

    const int rg  = tid & 3;
    const int bgr = (tid >> 2) & 7;
    const int kq  = tid >> 5;

    const float* Whh = dir ? Whhb : Whhf;

    float w[4][16];
#pragma unroll
    for (int r = 0; r < 4; ++r) {
        const float* wr = Whh + (size_t)(rg * H_ + u0 + r) * H_ + kq * 16;
#pragma unroll
        for (int q = 0; q < 4; ++q) {
            float4 v = *(const float4*)(wr + q * 4);
            w[r][q * 4 + 0] = v.x; w[r][q * 4 + 1] = v.y;
            w[r][q * 4 + 2] = v.z; w[r][q * 4 + 3] = v.w;
        }
    }
    if (tid < B_) sL[tid] = seqlen[tid];
    __syncthreads();

    const int ul = (tid >> 5) & 3, bb = tid & 31;
    float c_reg = 0.f;
    if (t0 > 0 && tid < 128)
        c_reg = cbuf[(size_t)(dir * 64 + wgd) * 128 + ul * 32 + bb];

    // initial xg: gate group t0>>2 (fused), then load xg(t0), xg(t0+1)
    if (fused) {
        if (tid == 0) {
            const int* xc = xgcnt + dir * 128 + (t0 >> 2);
            while (__hip_atomic_load(xc, __ATOMIC_RELAXED,
                                     __HIP_MEMORY_SCOPE_AGENT) < 8)
                __builtin_amdgcn_s_sleep(1);
        }
        __syncthreads();
    }
    float xv0 = 0.f, xv1 = 0.f, xv2 = 0.f, xv3 = 0.f;   // xg(t)
    float ya0 = 0.f, ya1 = 0.f, ya2 = 0.f, ya3 = 0.f;   // xg(t+1)
    if (tid < 128) {
        const float* xp = xg + (size_t)(dir * Tc) * 32768 + (u0 + ul) * 32 + bb;
        xv0 = __hip_atomic_load(xp,         __ATOMIC_RELAXED, __HIP_MEMORY_SCOPE_AGENT);
        xv1 = __hip_atomic_load(xp +  8192, __ATOMIC_RELAXED, __HIP_MEMORY_SCOPE_AGENT);
        xv2 = __hip_atomic_load(xp + 16384, __ATOMIC_RELAXED, __HIP_MEMORY_SCOPE_AGENT);
        xv3 = __hip_atomic_load(xp + 24576, __ATOMIC_RELAXED, __HIP_MEMORY_SCOPE_AGENT);
        if (Tc > 1) {
            const float* xq = xp + 32768;
            ya0 = __hip_atomic_load(xq,         __ATOMIC_RELAXED, __HIP_MEMORY_SCOPE_AGENT);
            ya1 = __hip_atomic_load(xq +  8192, __ATOMIC_RELAXED, __HIP_MEMORY_SCOPE_AGENT);
            ya2 = __hip_atomic_load(xq + 16384, __ATOMIC_RELAXED, __HIP_MEMORY_SCOPE_AGENT);
            ya3 = __hip_atomic_load(xq + 24576, __ATOMIC_RELAXED, __HIP_MEMORY_SCOPE_AGENT);
        }
    }

    for (int tc = 0; tc < Tc; ++tc) {
        const int t = t0 + tc;

        // [A] h(t-1): load packets, validate tags, SELECTIVE retry of stale.
        if (t > 0) {
            const u64* hp = hbuf + (size_t)(dir * 2 + ((t - 1) & 1)) * 8192;
            u64 hr[16];
#pragma unroll
            for (int i = 0; i < 16; ++i)
                hr[i] = __hip_atomic_load(hp + tid + 512 * i, __ATOMIC_RELAXED,
                                          __HIP_MEMORY_SCOPE_AGENT);
            for (;;) {
                unsigned bad = 0;
#pragma unroll
                for (int i = 0; i < 16; ++i)
                    if ((unsigned)(hr[i] >> 32) != (unsigned)t) bad |= (1u << i);
                if (__all(bad == 0)) break;
                __builtin_amdgcn_s_sleep(1);
#pragma unroll
                for (int i = 0; i < 16; ++i)
                    if (bad & (1u << i))
                        hr[i] = __hip_atomic_load(hp + tid + 512 * i,
                                                  __ATOMIC_RELAXED,
                                                  __HIP_MEMORY_SCOPE_AGENT);
            }
#pragma unroll
            for (int i = 0; i < 16; ++i) {
                int wdx = tid + 512 * i;                      // word 0..8191
                int k = ((wdx >> 7) << 2) | ((wdx >> 5) & 3); // unit
                int b = wdx & 31;                             // batch
                hP[((k >> 4) * 8 + (b >> 2)) * 68 + (k & 15) * 4 + (b & 3)] =
                    __uint_as_float((unsigned)hr[i]);
            }
        }
        __syncthreads();

        // non-blocking xgcnt peek for t+2 (waitcnt lands under the dot)
        int cnt = 8;
        if (fused && tc + 2 < Tc && tid < 128)
            cnt = __hip_atomic_load(xgcnt + dir * 128 + ((t0 + tc + 2) >> 2),
                                    __ATOMIC_RELAXED, __HIP_MEMORY_SCOPE_AGENT);

        // [B] dot (W from registers, h from conflict-free hP blocks)
        float acc[4][4];
#pragma unroll
        for (int r = 0; r < 4; ++r)
#pragma unroll
            for (int bi = 0; bi < 4; ++bi) acc[r][bi] = 0.f;

        if (t > 0) {
            const float* hblk = &hP[(kq * 8 + bgr) * 68];
#pragma unroll
            for (int kk = 0; kk < 16; ++kk) {
                float4 h4 = *(const float4*)(hblk + kk * 4);
#pragma unroll
                for (int r = 0; r < 4; ++r) {
                    acc[r][0] += w[r][kk] * h4.x;
                    acc[r][1] += w[r][kk] * h4.y;
                    acc[r][2] += w[r][kk] * h4.z;
                    acc[r][3] += w[r][kk] * h4.w;
                }
            }
        }

#pragma unroll
        for (int r = 0; r < 4; ++r)
#pragma unroll
            for (int bi = 0; bi < 4; ++bi)
                acc[r][bi] += __shfl_xor(acc[r][bi], 32, 64);

        if (((tid >> 5) & 1) == 0) {
            const int kq2 = kq >> 1;
#pragma unroll
            for (int r = 0; r < 4; ++r)
#pragma unroll
                for (int bi = 0; bi < 4; ++bi)
                    gbuf[(r * 4 + rg) * GROWP + (bgr * 4 + bi) * 9 + kq2] = acc[r][bi];
        }
        __syncthreads();

        // [C] epilogue + packet publish (tid<128)
        float hnew = 0.f;
        float* oaddr = nullptr;
        if (tid < 128) {
            const int u = u0 + ul;
            if (t < sL[bb]) {
                float gi = xv0, gf = xv1, gg = xv2, go = xv3;
#pragma unroll
                for (int q = 0; q < 8; ++q) {
                    gi += gbuf[(ul * 4 + 0) * GROWP + bb * 9 + q];
                    gf += gbuf[(ul * 4 + 1) * GROWP + bb * 9 + q];
                    gg += gbuf[(ul * 4 + 2) * GROWP + bb * 9 + q];
                    go += gbuf[(ul * 4 + 3) * GROWP + bb * 9 + q];
                }
                float si = 1.f / (1.f + expf(-gi));
                float sf = 1.f / (1.f + expf(-gf));
                float so = 1.f / (1.f + expf(-go));
                c_reg = sf * c_reg + si * tanhf(gg);
                hnew  = so * tanhf(c_reg);
                if (dir == 0) {
                    int j = fslot[bb * T_ + t];
                    if (j >= 0) oaddr = &out[((size_t)bb * OUT_ + j) * 512 + u];
                } else {
                    int p = bpos[bb * T_ + t];
                    if (p >= 0) oaddr = &out[((size_t)bb * OUT_ + p) * 512 + 256 + u];
                }
            } else {
                hnew = hP[((u >> 4) * 8 + (bb >> 2)) * 68 + (u & 15) * 4 + (bb & 3)];
            }
            // self-validating packet: {tag = t+1, value}; coalesced 1 KB
            u64 pkt = ((u64)(unsigned)(t + 1) << 32) | (u64)__float_as_uint(hnew);
            u64* hn = hbuf + (size_t)(dir * 2 + (t & 1)) * 8192;
            __hip_atomic_store(&hn[wgd * 128 + tid], pkt,
                               __ATOMIC_RELAXED, __HIP_MEMORY_SCOPE_AGENT);
        }
        __syncthreads();   // protect hP/gbuf; also throttles next-step spin

        // [D] off-critical tail: xg(t+2) load (+rare gate), out scatter
        float z0 = 0.f, z1 = 0.f, z2 = 0.f, z3 = 0.f;
        if (tc + 2 < Tc && tid < 128) {
            if (fused && cnt < 8) {
                const int* xc = xgcnt + dir * 128 + ((t0 + tc + 2) >> 2);
                while (__hip_atomic_load(xc, __ATOMIC_RELAXED,
                                         __HIP_MEMORY_SCOPE_AGENT) < 8)
                    __builtin_amdgcn_s_sleep(1);
            }
            const float* xp = xg + (size_t)(dir * Tc + tc + 2) * 32768 + (u0 + ul) * 32 + bb;
            z0 = __hip_atomic_load(xp,         __ATOMIC_RELAXED, __HIP_MEMORY_SCOPE_AGENT);
            z1 = __hip_atomic_load(xp +  8192, __ATOMIC_RELAXED, __HIP_MEMORY_SCOPE_AGENT);
            z2 = __hip_atomic_load(xp + 16384, __ATOMIC_RELAXED, __HIP_MEMORY_SCOPE_AGENT);
            z3 = __hip_atomic_load(xp + 24576, __ATOMIC_RELAXED, __HIP_MEMORY_SCOPE_AGENT);
        }
        if (oaddr)
            __hip_atomic_store(oaddr, hnew, __ATOMIC_RELAXED,
                               __HIP_MEMORY_SCOPE_AGENT);
        xv0 = ya0; xv1 = ya1; xv2 = ya2; xv3 = ya3;
        ya0 = z0;  ya1 = z1;  ya2 = z2;  ya3 = z3;
    }

    if (tid < 128)
        cbuf[(size_t)(dir * 64 + wgd) * 128 + ul * 32 + bb] = c_reg;
}

// ---------------------------------------------------------------------------
extern "C" void kernel_launch(void* const* d_in, const int* in_sizes, int n_in,
                              void* d_out, int out_size, void* d_ws, size_t ws_size,
                              hipStream_t stream) {
    const int*           inputs = (const int*)d_in[0];
    const int*           seqlen = (const int*)d_in[1];
    const unsigned char* fm     = (const unsigned char*)d_in[2];
    const unsigned char* bm     = (const unsigned char*)d_in[3];
    // d_in[4] = out_seq_length (== 256, hardcoded)
    const float* emb  = (const float*)d_in[5];
    const float* Wihf = (const float*)d_in[6];
    const float* Whhf = (const float*)d_in[7];
    const float* bihf = (const float*)d_in[8];
    const float* bhhf = (const float*)d_in[9];
    const float* Wihb = (const float*)d_in[10];
    const float* Whhb = (const float*)d_in[11];
    const float* bihb = (const float*)d_in[12];
    const float* bhhb = (const float*)d_in[13];
    float* out = (float*)d_out;

    char* ws = (char*)d_ws;
    // ws layout (bytes):
    //   [0)       fslot int32[32][512]                       65536
    //   [65536)   bpos  int32[32][512]                       65536
    //   [131072)  h packets u64[2dir][2par][8192]           262144
    //   [393216)  c checkpoint f32[2dir][64][4][32]          65536
    //   [458752)  xgcnt int32[2dir][128]                      1024
    //   [460800)  xg f32[2dir][Tc][1024][32]            Tc*262144
    int*   fslot = (int*)(ws);
    int*   bpos  = (int*)(ws + 65536);
    u64*   hbuf  = (u64*)(ws + 131072);
    float* cbuf  = (float*)(ws + 393216);
    int*   xgcnt = (int*)(ws + 458752);
    float* xg    = (float*)(ws + 460800);
    (void)in_sizes; (void)n_in; (void)out_size;

    size_t avail = (ws_size > 460800) ? ws_size - 460800 : 0;
    int Tc = 4;
    for (int c = 512; c >= 4; c >>= 1)
        if ((size_t)c * 262144 <= avail) { Tc = c; break; }

    // zero packet tags + xg counters every call (replay-safe: tag 0 is
    // never a valid expected tag since published tags are t+1 >= 1)
    (void)hipMemsetAsync(ws + 131072, 0, 262144, stream);
    (void)hipMemsetAsync(ws + 458752, 0, 1024, stream);
    slots_kernel<<<1, 64, 0, stream>>>(fm, bm, fslot, bpos);

    if (Tc == 512) {
        // fused: 128 recurrence WGs + 128 xg-producer WGs, one launch
        fused_lstm<<<256, 512, 0, stream>>>(
            inputs, seqlen, emb, Wihf, Whhf, bihf, bhhf,
            Wihb, Whhb, bihb, bhhb, fslot, bpos,
            hbuf, cbuf, xgcnt, xg, out, 0, 512, 1);
    } else {
        // fallback: chunked, separate gemm kernel (tags use global t, so
        // they remain consistent across chunk launches)
        for (int t0 = 0; t0 < T_; t0 += Tc) {
            dim3 g(16, Tc / 4, 2);
            xg_gemm<<<g, 256, 0, stream>>>(inputs, seqlen, emb, Wihf, Wihb,
                                           bihf, bhhf, bihb, bhhb, xg, t0, Tc);
            fused_lstm<<<128, 512, 0, stream>>>(
                inputs, seqlen, emb, Wihf, Whhf, bihf, bhhf,
                Wihb, Whhb, bihb, bhhb, fslot, bpos,
                hbuf, cbuf, xgcnt, xg, out, t0, Tc, 0);
        }
    }
}

// Round 16
// 2005.075 us; speedup vs baseline: 1.1235x; 1.0582x over previous
//
#include <hip/hip_runtime.h>
#include <hip/hip_bf16.h>

#define B_   32
#define T_   512
#define E_   300
#define H_   256
#define OUT_ 256
#define ECH  100    // gemm e-chunk (3 x 100 = 300)
#define GROWP 293   // gbuf row stride; conflict-free (banks 5rg+4bgr cover all 32)

typedef unsigned long long u64;

// ---------------------------------------------------------------------------
// Slot tables, LDS-staged (unchanged).
// ---------------------------------------------------------------------------
__global__ __launch_bounds__(64) void slots_kernel(
    const unsigned char* __restrict__ fm, const unsigned char* __restrict__ bm,
    int* __restrict__ fslot, int* __restrict__ bpos)
{
    __shared__ unsigned char fL[B_ * T_];
    __shared__ unsigned char bL[B_ * T_];
    const int tid = threadIdx.x;

    const unsigned int* fw = (const unsigned int*)fm;
    int cnt = 0;
    for (int i = tid; i < 128; i += 64) {
        unsigned int v = fw[i];
        cnt += ((v & 0xFFu) != 0) + ((v & 0xFF00u) != 0)
             + ((v & 0xFF0000u) != 0) + ((v >> 24) != 0);
    }
#pragma unroll
    for (int off = 32; off; off >>= 1) cnt += __shfl_down(cnt, off, 64);
    bool isbool = __shfl(cnt, 0, 64) > 128;

    if (isbool) {
        for (int i = tid; i < B_ * T_ / 4; i += 64) {
            ((unsigned int*)fL)[i] = ((const unsigned int*)fm)[i];
            ((unsigned int*)bL)[i] = ((const unsigned int*)bm)[i];
        }
    } else {
        const unsigned int* bw = (const unsigned int*)bm;
        for (int i = tid; i < B_ * T_; i += 64) {
            fL[i] = fw[i] != 0;
            bL[i] = bw[i] != 0;
        }
    }
    __syncthreads();

    if (tid < B_) {
        int jf = 0, jb = 0;
        for (int t = 0; t < T_; ++t) {
            bool f = fL[tid * T_ + t] != 0;
            bool g = bL[tid * T_ + t] != 0;
            fslot[tid * T_ + t] = f ? (jf++) : -1;
            bpos [tid * T_ + t] = g ? (OUT_ - 1 - (jb++)) : -1;
        }
    }
}

// ---------------------------------------------------------------------------
// Standalone xg GEMM — fallback only (ws too small for full-T xg buffer).
// ---------------------------------------------------------------------------
__global__ __launch_bounds__(256) void xg_gemm(
    const int* __restrict__ inputs, const int* __restrict__ seqlen,
    const float* __restrict__ emb,
    const float* __restrict__ Wihf, const float* __restrict__ Wihb,
    const float* __restrict__ bihf, const float* __restrict__ bhhf,
    const float* __restrict__ bihb, const float* __restrict__ bhhb,
    float* __restrict__ xg, int t0, int TcMax)
{
    const int tg   = blockIdx.y;
    const int dir  = blockIdx.z;
    const int rblk = blockIdx.x * 64;
    const int tid  = threadIdx.x;

    __shared__ float eL[4][B_][ECH];
    __shared__ int   tokS[4][B_];

    if (tid < 128) {
        int t4 = tid >> 5, b = tid & 31;
        int t = t0 + tg * 4 + t4;
        int L = seqlen[b];
        int tt = t;
        if (dir) tt = (t < L) ? (L - 1 - t) : t;
        tokS[t4][b] = inputs[b * T_ + tt];
    }

    const float* W = dir ? Wihb : Wihf;
    const int b  = tid & 31;
    const int r8 = tid >> 5;

    float acc[4][8];
#pragma unroll
    for (int t4 = 0; t4 < 4; ++t4)
#pragma unroll
        for (int m = 0; m < 8; ++m) acc[t4][m] = 0.f;

    for (int ec = 0; ec < 3; ++ec) {
        __syncthreads();
        for (int idx = tid; idx < 3200; idx += 256) {
            int q  = idx % 25;
            int bb = (idx / 25) & 31;
            int t4 = idx / (25 * 32);
            const float* erow = emb + (size_t)tokS[t4][bb] * E_ + ec * ECH;
            *(float4*)&eL[t4][bb][q * 4] = *(const float4*)(erow + q * 4);
        }
        __syncthreads();

        for (int e4 = 0; e4 < 25; ++e4) {
            float4 w4[8];
#pragma unroll
            for (int m = 0; m < 8; ++m)
                w4[m] = *(const float4*)(W + (size_t)(rblk + r8 + m * 8) * E_
                                         + ec * ECH + e4 * 4);
#pragma unroll
            for (int t4 = 0; t4 < 4; ++t4) {
                float4 h4 = *(const float4*)&eL[t4][b][e4 * 4];
#pragma unroll
                for (int m = 0; m < 8; ++m)
                    acc[t4][m] += h4.x * w4[m].x + h4.y * w4[m].y
                                + h4.z * w4[m].z + h4.w * w4[m].w;
            }
        }
    }

    const float* bi = dir ? bihb : bihf;
    const float* bh = dir ? bhhb : bhhf;
#pragma unroll
    for (int t4 = 0; t4 < 4; ++t4) {
        float* outp = xg + (size_t)(dir * TcMax + tg * 4 + t4) * (1024 * B_);
#pragma unroll
        for (int m = 0; m < 8; ++m) {
            int row = rblk + r8 + m * 8;
            outp[(size_t)row * B_ + b] = acc[t4][m] + bi[row] + bh[row];
        }
    }
}

// ---------------------------------------------------------------------------
// Fused kernel v3 (r13, best measured): TAG-IN-DATA h exchange.
// h published as u64 packets {hi = tag (t+1), lo = f32 bits} via bypass
// stores; consumers load packets and validate tags in-register -> flag
// system deleted, discovery and data are ONE LLC trip. Ping-pong + tags
// make overwrite race-free (a WG at t+1 proves everyone consumed t-1).
// Tag t+1 >= 1 != memset-0 -> replay-safe. xg prefetch 2 steps ahead,
// xgcnt checked non-blockingly under the dot.
// Retry is ALL-16 batched (r15's selective retry measured slower: divergent
// masked reloads + VGPR pressure outweigh the byte savings).
// ---------------------------------------------------------------------------
__global__ __launch_bounds__(512, 2) void fused_lstm(
    const int* __restrict__ inputs, const int* __restrict__ seqlen,
    const float* __restrict__ emb,
    const float* __restrict__ Wihf, const float* __restrict__ Whhf,
    const float* __restrict__ bihf, const float* __restrict__ bhhf,
    const float* __restrict__ Wihb, const float* __restrict__ Whhb,
    const float* __restrict__ bihb, const float* __restrict__ bhhb,
    const int* __restrict__ fslot, const int* __restrict__ bpos,
    u64* __restrict__ hbuf, float* __restrict__ cbuf,
    int* __restrict__ xgcnt, float* __restrict__ xg, float* __restrict__ out,
    int t0, int Tc, int fused)
{
    const int wg  = blockIdx.x;
    const int tid = threadIdx.x;
    __shared__ __align__(16) float smem[13824];   // 55.3 KB, carved per role

    if (wg >= 128) {
        // ---------------- producer role (fused mode only) ----------------
        float* eL   = smem;                        // [4][32][ECH] = 12800 f
        int*   tokS = (int*)(smem + 12800);        // [4][32]
        const int hw = wg - 128;

        for (int j = hw; j < 2048; j += 128) {     // job: (tg, dir, rblk-pair)
            const int tg  = j >> 4;
            const int dir = (j >> 3) & 1;
            const int rp  = j & 7;
            const int rblk = (rp * 2 + (tid >> 8)) * 64;

            if (tid < 128) {
                int t4 = tid >> 5, b = tid & 31;
                int t = tg * 4 + t4;
                int L = seqlen[b];
                int tt = t;
                if (dir) tt = (t < L) ? (L - 1 - t) : t;
                tokS[t4 * B_ + b] = inputs[b * T_ + tt];
            }

            const float* W  = dir ? Wihb : Wihf;
            const int ltid = tid & 255;
            const int b  = ltid & 31;
            const int r8 = ltid >> 5;

            float acc[4][8];
#pragma unroll
            for (int t4 = 0; t4 < 4; ++t4)
#pragma unroll
                for (int m = 0; m < 8; ++m) acc[t4][m] = 0.f;

            for (int ec = 0; ec < 3; ++ec) {
                __syncthreads();   // tokS ready / eL consumed
                for (int idx = tid; idx < 3200; idx += 512) {
                    int q  = idx % 25;
                    int bb = (idx / 25) & 31;
                    int t4 = idx / (25 * 32);
                    const float* erow = emb + (size_t)tokS[t4 * B_ + bb] * E_ + ec * ECH;
                    *(float4*)&eL[(t4 * B_ + bb) * ECH + q * 4] = *(const float4*)(erow + q * 4);
                }
                __syncthreads();

                for (int e4 = 0; e4 < 25; ++e4) {
                    float4 w4[8];
#pragma unroll
                    for (int m = 0; m < 8; ++m)
                        w4[m] = *(const float4*)(W + (size_t)(rblk + r8 + m * 8) * E_
                                                 + ec * ECH + e4 * 4);
#pragma unroll
                    for (int t4 = 0; t4 < 4; ++t4) {
                        float4 h4 = *(const float4*)&eL[(t4 * B_ + b) * ECH + e4 * 4];
#pragma unroll
                        for (int m = 0; m < 8; ++m)
                            acc[t4][m] += h4.x * w4[m].x + h4.y * w4[m].y
                                        + h4.z * w4[m].z + h4.w * w4[m].w;
                    }
                }
            }

            const float* bi = dir ? bihb : bihf;
            const float* bh = dir ? bhhb : bhhf;
#pragma unroll
            for (int t4 = 0; t4 < 4; ++t4) {
                float* outp = xg + (size_t)(dir * 512 + tg * 4 + t4) * (1024 * B_);
#pragma unroll
                for (int m = 0; m < 8; ++m) {
                    int row = rblk + r8 + m * 8;
                    __hip_atomic_store(&outp[(size_t)row * B_ + b],
                                       acc[t4][m] + bi[row] + bh[row],
                                       __ATOMIC_RELAXED, __HIP_MEMORY_SCOPE_AGENT);
                }
            }
            __syncthreads();   // per-wave vmcnt(0): all bypass stores at LLC
            if (tid == 0)
                __hip_atomic_fetch_add(&xgcnt[dir * 128 + tg], 1,
                                       __ATOMIC_RELAXED, __HIP_MEMORY_SCOPE_AGENT);
        }
        return;
    }

    // ------------------------- recurrence role -------------------------
    float* hP   = smem;                      // 8704 f (34.8 KB)
    float* gbuf = smem + 8704;               // 16*GROWP = 4688 f
    int*   sL   = (int*)(smem + 8704 + 4688);

    const int dir = wg >> 6;
    const int wgd = wg & 63;
    const int u0  = wgd * 4;

    const int rg  = tid & 3;
    const int bgr = (tid >> 2) & 7;
    const int kq  = tid >> 5;

    const float* Whh = dir ? Whhb : Whhf;

    float w[4][16];
#pragma unroll
    for (int r = 0; r < 4; ++r) {
        const float* wr = Whh + (size_t)(rg * H_ + u0 + r) * H_ + kq * 16;
#pragma unroll
        for (int q = 0; q < 4; ++q) {
            float4 v = *(const float4*)(wr + q * 4);
            w[r][q * 4 + 0] = v.x; w[r][q * 4 + 1] = v.y;
            w[r][q * 4 + 2] = v.z; w[r][q * 4 + 3] = v.w;
        }
    }
    if (tid < B_) sL[tid] = seqlen[tid];
    __syncthreads();

    const int ul = (tid >> 5) & 3, bb = tid & 31;
    float c_reg = 0.f;
    if (t0 > 0 && tid < 128)
        c_reg = cbuf[(size_t)(dir * 64 + wgd) * 128 + ul * 32 + bb];

    // initial xg: gate group t0>>2 (fused), then load xg(t0), xg(t0+1)
    if (fused) {
        if (tid == 0) {
            const int* xc = xgcnt + dir * 128 + (t0 >> 2);
            while (__hip_atomic_load(xc, __ATOMIC_RELAXED,
                                     __HIP_MEMORY_SCOPE_AGENT) < 8)
                __builtin_amdgcn_s_sleep(1);
        }
        __syncthreads();
    }
    float xv0 = 0.f, xv1 = 0.f, xv2 = 0.f, xv3 = 0.f;   // xg(t)
    float ya0 = 0.f, ya1 = 0.f, ya2 = 0.f, ya3 = 0.f;   // xg(t+1)
    if (tid < 128) {
        const float* xp = xg + (size_t)(dir * Tc) * 32768 + (u0 + ul) * 32 + bb;
        xv0 = __hip_atomic_load(xp,         __ATOMIC_RELAXED, __HIP_MEMORY_SCOPE_AGENT);
        xv1 = __hip_atomic_load(xp +  8192, __ATOMIC_RELAXED, __HIP_MEMORY_SCOPE_AGENT);
        xv2 = __hip_atomic_load(xp + 16384, __ATOMIC_RELAXED, __HIP_MEMORY_SCOPE_AGENT);
        xv3 = __hip_atomic_load(xp + 24576, __ATOMIC_RELAXED, __HIP_MEMORY_SCOPE_AGENT);
        if (Tc > 1) {
            const float* xq = xp + 32768;
            ya0 = __hip_atomic_load(xq,         __ATOMIC_RELAXED, __HIP_MEMORY_SCOPE_AGENT);
            ya1 = __hip_atomic_load(xq +  8192, __ATOMIC_RELAXED, __HIP_MEMORY_SCOPE_AGENT);
            ya2 = __hip_atomic_load(xq + 16384, __ATOMIC_RELAXED, __HIP_MEMORY_SCOPE_AGENT);
            ya3 = __hip_atomic_load(xq + 24576, __ATOMIC_RELAXED, __HIP_MEMORY_SCOPE_AGENT);
        }
    }

    for (int tc = 0; tc < Tc; ++tc) {
        const int t = t0 + tc;

        // [A] h(t-1): load packets, validate tags in-register, retry if stale.
        if (t > 0) {
            const u64* hp = hbuf + (size_t)(dir * 2 + ((t - 1) & 1)) * 8192;
            u64 hr[16];
            for (;;) {
#pragma unroll
                for (int i = 0; i < 16; ++i)
                    hr[i] = __hip_atomic_load(hp + tid + 512 * i, __ATOMIC_RELAXED,
                                              __HIP_MEMORY_SCOPE_AGENT);
                bool ok = true;
#pragma unroll
                for (int i = 0; i < 16; ++i)
                    ok &= ((unsigned)(hr[i] >> 32) == (unsigned)t);
                if (__all(ok)) break;
                __builtin_amdgcn_s_sleep(1);
            }
#pragma unroll
            for (int i = 0; i < 16; ++i) {
                int wdx = tid + 512 * i;                     // word index 0..8191
                int k = ((wdx >> 7) << 2) | ((wdx >> 5) & 3); // unit
                int b = wdx & 31;                             // batch
                hP[((k >> 4) * 8 + (b >> 2)) * 68 + (k & 15) * 4 + (b & 3)] =
                    __uint_as_float((unsigned)hr[i]);
            }
        }
        __syncthreads();

        // non-blocking xgcnt peek for t+2 (waitcnt lands under the dot)
        int cnt = 8;
        if (fused && tc + 2 < Tc && tid < 128)
            cnt = __hip_atomic_load(xgcnt + dir * 128 + ((t0 + tc + 2) >> 2),
                                    __ATOMIC_RELAXED, __HIP_MEMORY_SCOPE_AGENT);

        // [B] dot (W from registers, h from conflict-free hP blocks)
        float acc[4][4];
#pragma unroll
        for (int r = 0; r < 4; ++r)
#pragma unroll
            for (int bi = 0; bi < 4; ++bi) acc[r][bi] = 0.f;

        if (t > 0) {
            const float* hblk = &hP[(kq * 8 + bgr) * 68];
#pragma unroll
            for (int kk = 0; kk < 16; ++kk) {
                float4 h4 = *(const float4*)(hblk + kk * 4);
#pragma unroll
                for (int r = 0; r < 4; ++r) {
                    acc[r][0] += w[r][kk] * h4.x;
                    acc[r][1] += w[r][kk] * h4.y;
                    acc[r][2] += w[r][kk] * h4.z;
                    acc[r][3] += w[r][kk] * h4.w;
                }
            }
        }

#pragma unroll
        for (int r = 0; r < 4; ++r)
#pragma unroll
            for (int bi = 0; bi < 4; ++bi)
                acc[r][bi] += __shfl_xor(acc[r][bi], 32, 64);

        if (((tid >> 5) & 1) == 0) {
            const int kq2 = kq >> 1;
#pragma unroll
            for (int r = 0; r < 4; ++r)
#pragma unroll
                for (int bi = 0; bi < 4; ++bi)
                    gbuf[(r * 4 + rg) * GROWP + (bgr * 4 + bi) * 9 + kq2] = acc[r][bi];
        }
        __syncthreads();

        // [C] epilogue + packet publish (tid<128)
        float hnew = 0.f;
        float* oaddr = nullptr;
        if (tid < 128) {
            const int u = u0 + ul;
            if (t < sL[bb]) {
                float gi = xv0, gf = xv1, gg = xv2, go = xv3;
#pragma unroll
                for (int q = 0; q < 8; ++q) {
                    gi += gbuf[(ul * 4 + 0) * GROWP + bb * 9 + q];
                    gf += gbuf[(ul * 4 + 1) * GROWP + bb * 9 + q];
                    gg += gbuf[(ul * 4 + 2) * GROWP + bb * 9 + q];
                    go += gbuf[(ul * 4 + 3) * GROWP + bb * 9 + q];
                }
                float si = 1.f / (1.f + expf(-gi));
                float sf = 1.f / (1.f + expf(-gf));
                float so = 1.f / (1.f + expf(-go));
                c_reg = sf * c_reg + si * tanhf(gg);
                hnew  = so * tanhf(c_reg);
                if (dir == 0) {
                    int j = fslot[bb * T_ + t];
                    if (j >= 0) oaddr = &out[((size_t)bb * OUT_ + j) * 512 + u];
                } else {
                    int p = bpos[bb * T_ + t];
                    if (p >= 0) oaddr = &out[((size_t)bb * OUT_ + p) * 512 + 256 + u];
                }
            } else {
                hnew = hP[((u >> 4) * 8 + (bb >> 2)) * 68 + (u & 15) * 4 + (bb & 3)];
            }
            // self-validating packet: {tag = t+1, value}; coalesced 1 KB
            u64 pkt = ((u64)(unsigned)(t + 1) << 32) | (u64)__float_as_uint(hnew);
            u64* hn = hbuf + (size_t)(dir * 2 + (t & 1)) * 8192;
            __hip_atomic_store(&hn[wgd * 128 + tid], pkt,
                               __ATOMIC_RELAXED, __HIP_MEMORY_SCOPE_AGENT);
        }
        __syncthreads();   // protect hP/gbuf; also throttles next-step spin

        // [D] off-critical tail: xg(t+2) load (+rare gate), out scatter
        float z0 = 0.f, z1 = 0.f, z2 = 0.f, z3 = 0.f;
        if (tc + 2 < Tc && tid < 128) {
            if (fused && cnt < 8) {
                const int* xc = xgcnt + dir * 128 + ((t0 + tc + 2) >> 2);
                while (__hip_atomic_load(xc, __ATOMIC_RELAXED,
                                         __HIP_MEMORY_SCOPE_AGENT) < 8)
                    __builtin_amdgcn_s_sleep(1);
            }
            const float* xp = xg + (size_t)(dir * Tc + tc + 2) * 32768 + (u0 + ul) * 32 + bb;
            z0 = __hip_atomic_load(xp,         __ATOMIC_RELAXED, __HIP_MEMORY_SCOPE_AGENT);
            z1 = __hip_atomic_load(xp +  8192, __ATOMIC_RELAXED, __HIP_MEMORY_SCOPE_AGENT);
            z2 = __hip_atomic_load(xp + 16384, __ATOMIC_RELAXED, __HIP_MEMORY_SCOPE_AGENT);
            z3 = __hip_atomic_load(xp + 24576, __ATOMIC_RELAXED, __HIP_MEMORY_SCOPE_AGENT);
        }
        if (oaddr)
            __hip_atomic_store(oaddr, hnew, __ATOMIC_RELAXED,
                               __HIP_MEMORY_SCOPE_AGENT);
        xv0 = ya0; xv1 = ya1; xv2 = ya2; xv3 = ya3;
        ya0 = z0;  ya1 = z1;  ya2 = z2;  ya3 = z3;
    }

    if (tid < 128)
        cbuf[(size_t)(dir * 64 + wgd) * 128 + ul * 32 + bb] = c_reg;
}

// ---------------------------------------------------------------------------
extern "C" void kernel_launch(void* const* d_in, const int* in_sizes, int n_in,
                              void* d_out, int out_size, void* d_ws, size_t ws_size,
                              hipStream_t stream) {
    const int*           inputs = (const int*)d_in[0];
    const int*           seqlen = (const int*)d_in[1];
    const unsigned char* fm     = (const unsigned char*)d_in[2];
    const unsigned char* bm     = (const unsigned char*)d_in[3];
    // d_in[4] = out_seq_length (== 256, hardcoded)
    const float* emb  = (const float*)d_in[5];
    const float* Wihf = (const float*)d_in[6];
    const float* Whhf = (const float*)d_in[7];
    const float* bihf = (const float*)d_in[8];
    const float* bhhf = (const float*)d_in[9];
    const float* Wihb = (const float*)d_in[10];
    const float* Whhb = (const float*)d_in[11];
    const float* bihb = (const float*)d_in[12];
    const float* bhhb = (const float*)d_in[13];
    float* out = (float*)d_out;

    char* ws = (char*)d_ws;
    // ws layout (bytes):
    //   [0)       fslot int32[32][512]                       65536
    //   [65536)   bpos  int32[32][512]                       65536
    //   [131072)  h packets u64[2dir][2par][8192]           262144
    //   [393216)  c checkpoint f32[2dir][64][4][32]          65536
    //   [458752)  xgcnt int32[2dir][128]                      1024
    //   [460800)  xg f32[2dir][Tc][1024][32]            Tc*262144
    int*   fslot = (int*)(ws);
    int*   bpos  = (int*)(ws + 65536);
    u64*   hbuf  = (u64*)(ws + 131072);
    float* cbuf  = (float*)(ws + 393216);
    int*   xgcnt = (int*)(ws + 458752);
    float* xg    = (float*)(ws + 460800);
    (void)in_sizes; (void)n_in; (void)out_size;

    size_t avail = (ws_size > 460800) ? ws_size - 460800 : 0;
    int Tc = 4;
    for (int c = 512; c >= 4; c >>= 1)
        if ((size_t)c * 262144 <= avail) { Tc = c; break; }

    // zero packet tags + xg counters every call (replay-safe: tag 0 is
    // never a valid expected tag since published tags are t+1 >= 1)
    (void)hipMemsetAsync(ws + 131072, 0, 262144, stream);
    (void)hipMemsetAsync(ws + 458752, 0, 1024, stream);
    slots_kernel<<<1, 64, 0, stream>>>(fm, bm, fslot, bpos);

    if (Tc == 512) {
        // fused: 128 recurrence WGs + 128 xg-producer WGs, one launch
        fused_lstm<<<256, 512, 0, stream>>>(
            inputs, seqlen, emb, Wihf, Whhf, bihf, bhhf,
            Wihb, Whhb, bihb, bhhb, fslot, bpos,
            hbuf, cbuf, xgcnt, xg, out, 0, 512, 1);
    } else {
        // fallback: chunked, separate gemm kernel (tags use global t, so
        // they remain consistent across chunk launches)
        for (int t0 = 0; t0 < T_; t0 += Tc) {
            dim3 g(16, Tc / 4, 2);
            xg_gemm<<<g, 256, 0, stream>>>(inputs, seqlen, emb, Wihf, Wihb,
                                           bihf, bhhf, bihb, bhhb, xg, t0, Tc);
            fused_lstm<<<128, 512, 0, stream>>>(
                inputs, seqlen, emb, Wihf, Whhf, bihf, bhhf,
                Wihb, Whhb, bihb, bhhb, fslot, bpos,
                hbuf, cbuf, xgcnt, xg, out, t0, Tc, 0);
        }
    }
}